// Round 1
// 796.937 us; speedup vs baseline: 1.5838x; 1.5838x over previous
//
#include <hip/hip_runtime.h>
#include <math.h>

#define B 16
#define T 8192
#define C 1024
#define H 16
#define D 64

#define NCHUNK 32          // chunks per batch for fused kernel
#define CHUNK  256         // rows per block (T / NCHUNK)
#define RS     16          // rows per subtile
#define NST    (CHUNK/RS)  // subtiles per chunk

typedef unsigned short ushort_t;
typedef unsigned int uint_t;

typedef _Float16 half8  __attribute__((ext_vector_type(8)));
typedef _Float16 half4v __attribute__((ext_vector_type(4)));
typedef float    float4v __attribute__((ext_vector_type(4)));

// ---------------------------------------------------------------------------
// Workspace layout:
//   fdiv   : double[C]       div_term[pair]/(2*pi)
//   q      : B*C
//   rt     : B*C*H           Wk^T q per (b,c,h), scaled 1/8
//   cc     : B*H             bk.q per (b,h), scaled 1/8
//   sacc   : B*H*C           normalized softmax-weighted sum of x~
//   y      : B*C
//   pacc   : (B*NCHUNK)*H*C  per-chunk unnormalized weighted sums (32 MB)
//   pl     : (B*NCHUNK)*H    per-chunk denominators
// ---------------------------------------------------------------------------

__global__ void k_fdiv(double* __restrict__ fdiv) {
    int c = blockIdx.x * 256 + threadIdx.x;
    if (c < C) {
        int i2 = c & ~1;
        double e = exp((double)i2 * (-9.210340371976184 / 1024.0)); // -ln(10000)/C
        fdiv[c] = e * 0.15915494309189535;                          // /(2*pi)
    }
}

// q[b][c] = bq[c] + sum_k x~[b,0,k] * Wq[k][c]   (PE(0,k) = k odd ? 1 : 0)
__global__ void __launch_bounds__(256) k_q(const float* __restrict__ x,
                                           const float* __restrict__ Wq,
                                           const float* __restrict__ bq,
                                           float* __restrict__ q) {
    __shared__ float xs[C];
    __shared__ float red[4][64];
    int b = blockIdx.x >> 4;
    int cblk = blockIdx.x & 15;
    const float* xrow = x + (size_t)b * T * C;
    for (int i = threadIdx.x; i < C; i += 256)
        xs[i] = xrow[i] + ((i & 1) ? 1.0f : 0.0f);
    __syncthreads();
    int col = threadIdx.x & 63;
    int kg  = threadIdx.x >> 6;
    int c = cblk * 64 + col;
    float acc = 0.f;
#pragma unroll 8
    for (int k = kg * 256; k < kg * 256 + 256; ++k)
        acc += xs[k] * Wq[(size_t)k * C + c];
    red[kg][col] = acc;
    __syncthreads();
    if (kg == 0)
        q[b * C + c] = bq[c] + red[0][col] + red[1][col] + red[2][col] + red[3][col];
}

// rt[b][c][h] = 0.125 * sum_d Wkv[c][h*64+d] * q[b][h*64+d]
__global__ void __launch_bounds__(256) k_rt(const float* __restrict__ Wkv,
                                            const float* __restrict__ bkv,
                                            const float* __restrict__ q,
                                            float* __restrict__ rt,
                                            float* __restrict__ cc) {
    __shared__ float qs[D];
    int b = blockIdx.x >> 4, h = blockIdx.x & 15;
    if (threadIdx.x < D) qs[threadIdx.x] = q[b * C + h * D + threadIdx.x];
    __syncthreads();
    for (int c = threadIdx.x; c < C; c += 256) {
        const float4* wrow = (const float4*)(Wkv + (size_t)c * (2 * C) + h * D);
        float acc = 0.f;
#pragma unroll
        for (int d4 = 0; d4 < D / 4; ++d4) {
            float4 w = wrow[d4];
            acc += w.x * qs[d4 * 4 + 0] + w.y * qs[d4 * 4 + 1] +
                   w.z * qs[d4 * 4 + 2] + w.w * qs[d4 * 4 + 3];
        }
        rt[((size_t)b * C + c) * H + h] = acc * 0.125f;
    }
    if (threadIdx.x == 0) {
        float acc = 0.f;
        for (int d = 0; d < D; ++d) acc += bkv[h * D + d] * qs[d];
        cc[b * H + h] = acc * 0.125f;
    }
}

// ---------------------------------------------------------------------------
// Fused single pass over x: PE + scores (fp16 MFMA, split-rt for fp32-grade
// accuracy) + exp (no max: softmax ratio is shift-invariant, |s|<=~40 so no
// overflow in fp32) + weighted accumulation (fp32 VALU, fp16 x~).
// Grid: B*NCHUNK = 512 blocks, 256 threads (4 waves), 2 blocks/CU resident.
// ---------------------------------------------------------------------------
__global__ void __launch_bounds__(256, 2)
k_fused(const float* __restrict__ x,
        const float* __restrict__ rt,
        const float* __restrict__ cc,
        const double* __restrict__ fdiv,
        float* __restrict__ pacc,
        float* __restrict__ pl) {
    __shared__ _Float16 xa[RS * 1024];   // x~ subtile, fp16, XOR-swizzled rows
    __shared__ float Sred[4 * RS * 16];  // per-wave partial scores
    __shared__ float p_lds[RS * 16];     // exp(scores) for subtile
    __shared__ float l_lds[16];          // running denominator per head
    __shared__ float cc_sh[16];

    const int tid = threadIdx.x;
    const int b  = blockIdx.x >> 5;
    const int t0 = (blockIdx.x & 31) * CHUNK;
    const int lane = tid & 63;
    const int wv   = tid >> 6;
    const int c0   = tid * 4;

    if (tid < 16) { cc_sh[tid] = cc[b * H + tid]; l_lds[tid] = 0.f; }

    // rt fragments (fp16 hi+lo) in B-operand layout for mfma_f32_16x16x32_f16.
    // Wave wv owns K-range c in [wv*256, wv*256+256) -> 8 k-steps of 32.
    const int m = lane & 15, g = lane >> 4;
    half8 rhf[8], rlf[8];
#pragma unroll
    for (int ks = 0; ks < 8; ++ks) {
#pragma unroll
        for (int j = 0; j < 8; ++j) {
            int c = wv * 256 + ks * 32 + g * 8 + j;
            float v = rt[((size_t)b * C + c) * H + m];
            _Float16 hi = (_Float16)v;
            rhf[ks][j] = hi;
            rlf[ks][j] = (_Float16)(v - (float)hi);
        }
    }

    // per-thread PE constants (pairs (c0,c0+1) and (c0+2,c0+3))
    const double fd0 = fdiv[c0];
    const double fd1 = fdiv[c0 + 2];

    const float* xbase = x + ((size_t)b * T + t0) * C + c0;

    float4v acc[16];
#pragma unroll
    for (int h = 0; h < 16; ++h) acc[h] = (float4v){0.f, 0.f, 0.f, 0.f};

    auto stage = [&](int st) {
        const float* xs = xbase + (size_t)st * RS * C;
#pragma unroll 4
        for (int r = 0; r < RS; ++r) {
            float4v xv = *(const float4v*)(xs + (size_t)r * C);
            double td = (double)(t0 + st * RS + r);
            double rev0 = td * fd0;
            double rev1 = td * fd1;
            float a0 = (float)(rev0 - floor(rev0)) * 6.283185307179586f;
            float a1 = (float)(rev1 - floor(rev1)) * 6.283185307179586f;
            float sn0, cs0, sn1, cs1;
            __sincosf(a0, &sn0, &cs0);
            __sincosf(a1, &sn1, &cs1);
            half4v hv;
            hv[0] = (_Float16)(xv[0] + sn0);
            hv[1] = (_Float16)(xv[1] + cs0);
            hv[2] = (_Float16)(xv[2] + sn1);
            hv[3] = (_Float16)(xv[3] + cs1);
            int elem = (r * 1024 + c0) ^ ((r & 7) << 3);   // byte ^= (row&7)<<4
            *(half4v*)&xa[elem] = hv;
        }
    };

    stage(0);
    __syncthreads();

    for (int st = 0; st < NST; ++st) {
        // ---- phase A: partial scores via fp16 MFMA (split rt: hi + lo) ----
        float4v sac = {0.f, 0.f, 0.f, 0.f};
        const int abase = m * 1024 + wv * 256 + g * 8;
        const int aswz  = (m & 7) << 3;
#pragma unroll
        for (int ks = 0; ks < 8; ++ks) {
            half8 af = *(const half8*)&xa[(abase + ks * 32) ^ aswz];
            sac = __builtin_amdgcn_mfma_f32_16x16x32_f16(af, rhf[ks], sac, 0, 0, 0);
            sac = __builtin_amdgcn_mfma_f32_16x16x32_f16(af, rlf[ks], sac, 0, 0, 0);
        }
#pragma unroll
        for (int rg = 0; rg < 4; ++rg)
            Sred[wv * 256 + (g * 4 + rg) * 16 + m] = sac[rg];
        __syncthreads();

        // ---- reduce over waves + exp (thread = (r = tid>>4, h = tid&15)) ----
        {
            float s = Sred[tid] + Sred[256 + tid] + Sred[512 + tid] + Sred[768 + tid]
                    + cc_sh[tid & 15];
            p_lds[tid] = __expf(s);
        }
        __syncthreads();

        // ---- phase C: acc[h][c0..c0+3] += p[r][h] * x~[r][c0..c0+3] ----
        if (tid < 16) {
            float ls = 0.f;
#pragma unroll
            for (int r = 0; r < RS; ++r) ls += p_lds[r * 16 + tid];
            l_lds[tid] += ls;
        }
#pragma unroll 2
        for (int r = 0; r < RS; ++r) {
            int elem = (r * 1024 + c0) ^ ((r & 7) << 3);
            half4v xv = *(const half4v*)&xa[elem];
            float4v xvf = {(float)xv[0], (float)xv[1], (float)xv[2], (float)xv[3]};
            const float4v* pr = (const float4v*)&p_lds[r * 16];
            float4v p0 = pr[0], p1 = pr[1], p2 = pr[2], p3 = pr[3];
            float pvv[16] = {p0[0], p0[1], p0[2], p0[3],
                             p1[0], p1[1], p1[2], p1[3],
                             p2[0], p2[1], p2[2], p2[3],
                             p3[0], p3[1], p3[2], p3[3]};
#pragma unroll
            for (int h = 0; h < 16; ++h)
                acc[h] += xvf * pvv[h];
        }
        __syncthreads();
        if (st + 1 < NST) stage(st + 1);
        __syncthreads();
    }

    // ---- epilogue: write unnormalized partials ----
    float* pb = pacc + (size_t)blockIdx.x * (H * C) + c0;
#pragma unroll
    for (int h = 0; h < 16; ++h)
        *(float4v*)&pb[h * 1024] = acc[h];
    if (tid < 16) pl[blockIdx.x * 16 + tid] = l_lds[tid];
}

// sacc[b][h][c] = (sum_ch pacc[b,ch][h][c]) / (sum_ch pl[b,ch][h])
__global__ void __launch_bounds__(256) k_combine(const float* __restrict__ pacc,
                                                 const float* __restrict__ pl,
                                                 float* __restrict__ sacc) {
    int b = blockIdx.x >> 4, h = blockIdx.x & 15;
    float l = 0.f;
#pragma unroll
    for (int ch = 0; ch < NCHUNK; ++ch)
        l += pl[((b << 5) + ch) * 16 + h];
    float inv = 1.0f / l;
    int c0 = threadIdx.x * 4;
    float4v s = {0.f, 0.f, 0.f, 0.f};
#pragma unroll 4
    for (int ch = 0; ch < NCHUNK; ++ch)
        s += *(const float4v*)&pacc[(((size_t)(b << 5) + ch) * 16 + h) * 1024 + c0];
    s *= inv;
    *(float4v*)&sacc[((size_t)(b * 16 + h)) * 1024 + c0] = s;
}

// y[b][h*64+col] = bv[...] + sum_c sacc[b][h][c] * Wv[c][h*64+col]
__global__ void __launch_bounds__(256) k_y(const float* __restrict__ Wkv,
                                           const float* __restrict__ bkv,
                                           const float* __restrict__ sacc,
                                           float* __restrict__ y) {
    __shared__ float sl[C];
    __shared__ float red[4][64];
    int b = blockIdx.x >> 4, h = blockIdx.x & 15;
    for (int i = threadIdx.x; i < C; i += 256)
        sl[i] = sacc[(size_t)(b * H + h) * C + i];
    __syncthreads();
    int col = threadIdx.x & 63;
    int kg  = threadIdx.x >> 6;
    int cy = h * 64 + col;
    float acc = 0.f;
#pragma unroll 8
    for (int c = kg * 256; c < kg * 256 + 256; ++c)
        acc += sl[c] * Wkv[(size_t)c * (2 * C) + C + cy];
    red[kg][col] = acc;
    __syncthreads();
    if (kg == 0)
        y[b * C + cy] = bkv[C + cy] + red[0][col] + red[1][col] + red[2][col] + red[3][col];
}

// out[b][j] = bo[j] + sum_k y[b][k] * Wo[k][j];  grid B*16
__global__ void __launch_bounds__(256) k_out(const float* __restrict__ Wo,
                                             const float* __restrict__ bo,
                                             const float* __restrict__ y,
                                             float* __restrict__ out) {
    __shared__ float yl[C];
    __shared__ float red[4][64];
    int b = blockIdx.x >> 4, jb = blockIdx.x & 15;
    for (int i = threadIdx.x; i < C; i += 256) yl[i] = y[b * C + i];
    __syncthreads();
    int col = threadIdx.x & 63;
    int kg  = threadIdx.x >> 6;
    int j = jb * 64 + col;
    float acc = 0.f;
#pragma unroll 8
    for (int k = kg * 256; k < kg * 256 + 256; ++k)
        acc += yl[k] * Wo[(size_t)k * C + j];
    red[kg][col] = acc;
    __syncthreads();
    if (kg == 0)
        out[b * C + j] = bo[j] + red[0][col] + red[1][col] + red[2][col] + red[3][col];
}

extern "C" void kernel_launch(void* const* d_in, const int* in_sizes, int n_in,
                              void* d_out, int out_size, void* d_ws, size_t ws_size,
                              hipStream_t stream) {
    const float* x   = (const float*)d_in[0];
    const float* Wq  = (const float*)d_in[1];
    const float* bq  = (const float*)d_in[2];
    const float* Wkv = (const float*)d_in[3];
    const float* bkv = (const float*)d_in[4];
    const float* Wo  = (const float*)d_in[5];
    const float* bo  = (const float*)d_in[6];
    float* out = (float*)d_out;

    char* w = (char*)d_ws;
    double* fdiv = (double*)w;                           // 8 KB
    float* q     = (float*)(w + 8192);
    float* rt    = q + (size_t)B * C;
    float* cc    = rt + (size_t)B * C * H;
    float* sacc  = cc + B * H;
    float* y     = sacc + (size_t)B * H * C;
    float* pacc  = y + B * C;                            // 32 MB
    float* pl    = pacc + (size_t)(B * NCHUNK) * H * C;

    k_fdiv<<<4, 256, 0, stream>>>(fdiv);
    k_q<<<B * 16, 256, 0, stream>>>(x, Wq, bq, q);
    k_rt<<<B * H, 256, 0, stream>>>(Wkv, bkv, q, rt, cc);
    k_fused<<<B * NCHUNK, 256, 0, stream>>>(x, rt, cc, fdiv, pacc, pl);
    k_combine<<<B * H, 256, 0, stream>>>(pacc, pl, sacc);
    k_y<<<B * 16, 256, 0, stream>>>(Wkv, bkv, sacc, y);
    k_out<<<B * 16, 256, 0, stream>>>(Wo, bo, y, out);
}